// Round 11
// baseline (356.474 us; speedup 1.0000x reference)
//
#include <hip/hip_runtime.h>
#include <hip/hip_bf16.h>

#define NN    50000   // nodes
#define MP    50048   // padded to 128*391 for MFMA GEMM
#define E0C   400000  // raw edges
#define ETOT  450000  // + self loops
#define HH    8
#define FF    512     // H*C layers 1-2
#define F3    40      // H*C3 layer 3
#define C3    5
#define MAXE  128     // LDS alpha-cache capacity (deg ~ Poisson(8)+1)
#define NBLK  ((NN + 1023) / 1024)   // 49 scan blocks
#define MT2   (MP / 128)             // 391 m-tiles layer-2 gemm
#define GT2   (MT2 * 4)              // 1564 blocks

typedef __attribute__((ext_vector_type(8))) short bf16x8;
typedef __attribute__((ext_vector_type(8))) short s16x8;
typedef __attribute__((ext_vector_type(4))) float f32x4;

__device__ inline unsigned short f2bf(float f) {
    union { float f; unsigned int u; } v; v.f = f;
    unsigned int r = v.u + 0x7FFF + ((v.u >> 16) & 1);
    return (unsigned short)(r >> 16);
}
__device__ inline float bf2f(unsigned short u) {
    union { unsigned int i; float f; } v; v.i = ((unsigned int)u) << 16;
    return v.f;
}

// ---------------- CSR build ----------------
__global__ void count_kernel(const int* __restrict__ ei, int* __restrict__ cnt) {
    int e = blockIdx.x * blockDim.x + threadIdx.x;
    if (e >= ETOT) return;
    int dst = (e < E0C) ? ei[E0C + e] : (e - E0C);
    atomicAdd(&cnt[dst], 1);
}

__global__ __launch_bounds__(1024) void scan_blocks(const int* __restrict__ cnt,
                                                    int* __restrict__ offs,
                                                    int* __restrict__ bsum) {
    __shared__ int s[1024];
    int tid = threadIdx.x;
    int i = blockIdx.x * 1024 + tid;
    s[tid] = (i < NN) ? cnt[i] : 0;
    __syncthreads();
    for (int d = 1; d < 1024; d <<= 1) {
        int add = (tid >= d) ? s[tid - d] : 0;
        __syncthreads();
        s[tid] += add;
        __syncthreads();
    }
    if (i < NN) offs[i + 1] = s[tid];
    if (tid == 1023) bsum[blockIdx.x] = s[1023];
}

// scan_add with integrated carry: wave 0 sums bsum[0..blockIdx.x-1] in-kernel
// (replaces the separate scan_sums dispatch).
__global__ __launch_bounds__(1024) void scan_add(int* __restrict__ offs,
                                                 const int* __restrict__ bsum) {
    __shared__ int pref;
    int tid = threadIdx.x;
    if (tid < 64) {
        int v = (tid < blockIdx.x) ? bsum[tid] : 0;   // NBLK=49 <= 64
#pragma unroll
        for (int d = 32; d; d >>= 1) v += __shfl_xor(v, d);
        if (tid == 0) pref = v;
    }
    __syncthreads();
    int i = blockIdx.x * 1024 + tid;
    if (i < NN) offs[i + 1] += pref;
    if (i == 0) offs[0] = 0;
}

__global__ void scatter_kernel(const int* __restrict__ ei, const int* __restrict__ offs,
                               int* __restrict__ cur, int* __restrict__ srcs) {
    int e = blockIdx.x * blockDim.x + threadIdx.x;
    if (e >= ETOT) return;
    int src, dst;
    if (e < E0C) { src = ei[e]; dst = ei[E0C + e]; }
    else         { src = dst = e - E0C; }
    int pos = offs[dst] + atomicAdd(&cur[dst], 1);
    srcs[pos] = src;
}

// ---------------- fused prep: W2T + W3T + A2 tail zero (one dispatch) --------
__global__ void prep_all(const float* __restrict__ W2, const float* __restrict__ W3,
                         unsigned short* __restrict__ W2T, unsigned short* __restrict__ W3T,
                         unsigned short* __restrict__ A2) {
    int i = blockIdx.x * blockDim.x + threadIdx.x;
    if (i < FF * FF) {
        int n = i >> 9, k = i & 511;
        W2T[i] = f2bf(W2[k * FF + n]);
        return;
    }
    int j = i - FF * FF;
    if (j < 48 * 512) {
        int n = j >> 9, k = j & 511;
        W3T[j] = (n < F3) ? f2bf(W3[k * F3 + n]) : 0;
        return;
    }
    int l = j - 48 * 512;
    if (l < (MP - NN) * FF) A2[(size_t)NN * FF + l] = 0;
}

// ---------------- layer 1 GEMM (K=12) fused with logits, 64 nodes/block ------
__global__ __launch_bounds__(256) void gemm1_fused(
    const float* __restrict__ x, const float* __restrict__ W1,
    const float* __restrict__ as1, const float* __restrict__ ad1,
    unsigned short* __restrict__ hb, float* __restrict__ al_s,
    float* __restrict__ al_d) {
    __shared__ float xs[64 * 12];
    int t = threadIdx.x;
    int n0 = blockIdx.x * 64;
    int nvalid = NN - n0; if (nvalid > 64) nvalid = 64;

    for (int j = t; j < nvalid * 12; j += 256) xs[j] = x[(size_t)n0 * 12 + j];
    __syncthreads();

    int f = t * 2;
    float w0[12], w1[12];
#pragma unroll
    for (int k = 0; k < 12; ++k) {
        float2 wv = *(const float2*)&W1[k * FF + f];
        w0[k] = wv.x; w1[k] = wv.y;
    }
    float2 asv = *(const float2*)&as1[f];
    float2 adv = *(const float2*)&ad1[f];
    int head = t >> 5;

    for (int ni = 0; ni < nvalid; ++ni) {
        const float* xp = &xs[ni * 12];
        float4 xa = *(const float4*)xp;
        float4 xb = *(const float4*)(xp + 4);
        float4 xc = *(const float4*)(xp + 8);
        float xv[12] = {xa.x, xa.y, xa.z, xa.w, xb.x, xb.y, xb.z, xb.w,
                        xc.x, xc.y, xc.z, xc.w};
        float h0 = 0.f, h1 = 0.f;
#pragma unroll
        for (int k = 0; k < 12; ++k) { h0 += xv[k] * w0[k]; h1 += xv[k] * w1[k]; }
        unsigned int u = ((unsigned int)f2bf(h1) << 16) | f2bf(h0);
        *(unsigned int*)&hb[(size_t)(n0 + ni) * FF + f] = u;
        float ps = h0 * asv.x + h1 * asv.y;
        float pd = h0 * adv.x + h1 * adv.y;
#pragma unroll
        for (int d = 1; d < 32; d <<= 1) {
            ps += __shfl_xor(ps, d);
            pd += __shfl_xor(pd, d);
        }
        if ((t & 31) == 0) {
            al_s[(size_t)(n0 + ni) * HH + head] = ps;
            al_d[(size_t)(n0 + ni) * HH + head] = pd;
        }
    }
}

// ---------------- attention aggregate: ONE WAVE PER NODE, bf16 gather ----------
__global__ __launch_bounds__(256) void attn_gather(
    const unsigned short* __restrict__ Hb,   // [*,FF] bf16
    const float* __restrict__ alS, const float* __restrict__ alD,
    const int* __restrict__ offs, const int* __restrict__ srcs,
    const float* __restrict__ bias,
    float* __restrict__ out_f32, unsigned short* __restrict__ out_b16, int relu) {
    __shared__ float alpha_sh[4][MAXE][HH];
    __shared__ int   srcs_sh[4][MAXE];
    int w = threadIdx.x >> 6, lane = threadIdx.x & 63;
    int n = blockIdx.x * 4 + w;
    if (n >= NN) return;
    int h = lane >> 3, es = lane & 7;
    int beg = offs[n], end = offs[n + 1], deg = end - beg;

    float ald = alD[n * HH + h];
    float m = -1e30f, den = 0.f, idn;

    if (deg <= MAXE) {
        for (int e = es; e < deg; e += 8) {
            int s = srcs[beg + e];
            if (h == 0) srcs_sh[w][e] = s;
            float sc = alS[s * HH + h] + ald;
            sc = sc > 0.f ? sc : 0.2f * sc;
            alpha_sh[w][e][h] = sc;
            m = fmaxf(m, sc);
        }
        m = fmaxf(m, __shfl_xor(m, 1));
        m = fmaxf(m, __shfl_xor(m, 2));
        m = fmaxf(m, __shfl_xor(m, 4));
        for (int e = es; e < deg; e += 8) {
            float ex = __expf(alpha_sh[w][e][h] - m);
            den += ex;
            alpha_sh[w][e][h] = ex;
        }
        den += __shfl_xor(den, 1);
        den += __shfl_xor(den, 2);
        den += __shfl_xor(den, 4);
        idn = 1.f / (den + 1e-16f);
    } else {
        for (int e = es; e < deg; e += 8) {
            int s = srcs[beg + e];
            float sc = alS[s * HH + h] + ald;
            sc = sc > 0.f ? sc : 0.2f * sc;
            m = fmaxf(m, sc);
        }
        m = fmaxf(m, __shfl_xor(m, 1));
        m = fmaxf(m, __shfl_xor(m, 2));
        m = fmaxf(m, __shfl_xor(m, 4));
        for (int e = es; e < deg; e += 8) {
            int s = srcs[beg + e];
            float sc = alS[s * HH + h] + ald;
            sc = sc > 0.f ? sc : 0.2f * sc;
            den += __expf(sc - m);
        }
        den += __shfl_xor(den, 1);
        den += __shfl_xor(den, 2);
        den += __shfl_xor(den, 4);
        idn = 1.f / (den + 1e-16f);
    }

    int f0 = lane * 8;
    float acc[8] = {};
    if (deg <= MAXE) {
        int e = 0;
        for (; e + 4 <= deg; e += 4) {
            int s0 = srcs_sh[w][e + 0], s1 = srcs_sh[w][e + 1];
            int s2 = srcs_sh[w][e + 2], s3 = srcs_sh[w][e + 3];
            bf16x8 v0 = *(const bf16x8*)&Hb[(size_t)s0 * FF + f0];
            bf16x8 v1 = *(const bf16x8*)&Hb[(size_t)s1 * FF + f0];
            bf16x8 v2 = *(const bf16x8*)&Hb[(size_t)s2 * FF + f0];
            bf16x8 v3 = *(const bf16x8*)&Hb[(size_t)s3 * FF + f0];
            float a0 = alpha_sh[w][e + 0][h], a1 = alpha_sh[w][e + 1][h];
            float a2 = alpha_sh[w][e + 2][h], a3 = alpha_sh[w][e + 3][h];
#pragma unroll
            for (int k = 0; k < 8; ++k) {
                acc[k] += a0 * bf2f((unsigned short)v0[k]);
                acc[k] += a1 * bf2f((unsigned short)v1[k]);
                acc[k] += a2 * bf2f((unsigned short)v2[k]);
                acc[k] += a3 * bf2f((unsigned short)v3[k]);
            }
        }
        for (; e < deg; ++e) {
            int s = srcs_sh[w][e];
            float a = alpha_sh[w][e][h];
            bf16x8 v = *(const bf16x8*)&Hb[(size_t)s * FF + f0];
#pragma unroll
            for (int k = 0; k < 8; ++k)
                acc[k] += a * bf2f((unsigned short)v[k]);
        }
#pragma unroll
        for (int k = 0; k < 8; ++k) acc[k] *= idn;
    } else {
        for (int e = 0; e < deg; ++e) {
            int s = srcs[beg + e];
            float sc = alS[s * HH + h] + ald;
            sc = sc > 0.f ? sc : 0.2f * sc;
            float a = __expf(sc - m) * idn;
            bf16x8 v = *(const bf16x8*)&Hb[(size_t)s * FF + f0];
#pragma unroll
            for (int k = 0; k < 8; ++k)
                acc[k] += a * bf2f((unsigned short)v[k]);
        }
    }
    float4 b0 = *(const float4*)&bias[f0];
    float4 b1 = *(const float4*)&bias[f0 + 4];
    float bv[8] = {b0.x, b0.y, b0.z, b0.w, b1.x, b1.y, b1.z, b1.w};
    float vv[8];
#pragma unroll
    for (int k = 0; k < 8; ++k) {
        float t = acc[k] + bv[k];
        vv[k] = relu ? fmaxf(t, 0.f) : t;
    }
    if (out_f32) {
        float4 o0 = {vv[0], vv[1], vv[2], vv[3]};
        float4 o1 = {vv[4], vv[5], vv[6], vv[7]};
        *(float4*)&out_f32[(size_t)n * FF + f0] = o0;
        *(float4*)&out_f32[(size_t)n * FF + f0 + 4] = o1;
    }
    if (out_b16) {
        s16x8 ov;
#pragma unroll
        for (int k = 0; k < 8; ++k) ov[k] = (short)f2bf(vv[k]);
        *(s16x8*)&out_b16[(size_t)n * FF + f0] = ov;
    }
}

// ---------------- bf16 MFMA GEMM + fused logits, bf16 output ----------------
// Single-buffered (32KB LDS -> higher occupancy; dbuf measured neutral at this
// tile per m97/m99). L2-affinity swizzle retained.
__global__ __launch_bounds__(256) void gemm_mfma(
    const unsigned short* __restrict__ A,   // [MP][K] bf16
    const unsigned short* __restrict__ BT,  // [N][K]  bf16
    const float* __restrict__ a_s, const float* __restrict__ a_d,  // [N]
    unsigned short* __restrict__ Cb,        // [MP][N] bf16
    float* __restrict__ alS, float* __restrict__ alD,              // [MP][HH]
    int N, int K) {
    __shared__ unsigned short As[128 * 64];
    __shared__ unsigned short Bs[128 * 64];
    int t = threadIdx.x;
    int wave = t >> 6, lane = t & 63;
    int wr = wave >> 1, wc = wave & 1;

    // bijective bid -> (mt, nt): same-m blocks 8 apart in dispatch order.
    int bid = blockIdx.x;
    int mt, nt;
    if (bid < (MT2 / 8) * 32) {
        int g = bid >> 5, r = bid & 31;
        mt = g * 8 + (r & 7);
        nt = r >> 3;
    } else {
        int t2 = bid - (MT2 / 8) * 32;
        mt = (MT2 / 8) * 8 + (t2 >> 2);
        nt = t2 & 3;
    }
    int m0 = mt * 128, n0 = nt * 128;

    f32x4 acc[4][4] = {};
    int kg = lane >> 4;
    int lr = lane & 15;

    for (int k0 = 0; k0 < K; k0 += 64) {
#pragma unroll
        for (int q = 0; q < 4; ++q) {
            int c   = q * 256 + t;
            int row = c >> 3, kc = c & 7;
            int kcs = kc ^ (row & 7);
            const unsigned short* ga = A + (size_t)(m0 + row) * K + k0 + kcs * 8;
            const unsigned short* gb = BT + (size_t)(n0 + row) * K + k0 + kcs * 8;
            unsigned short* la = As + (size_t)(q * 256 + wave * 64) * 8;
            unsigned short* lb = Bs + (size_t)(q * 256 + wave * 64) * 8;
            __builtin_amdgcn_global_load_lds(
                (const __attribute__((address_space(1))) void*)ga,
                (__attribute__((address_space(3))) void*)la, 16, 0, 0);
            __builtin_amdgcn_global_load_lds(
                (const __attribute__((address_space(1))) void*)gb,
                (__attribute__((address_space(3))) void*)lb, 16, 0, 0);
        }
        __syncthreads();
#pragma unroll
        for (int ks = 0; ks < 2; ++ks) {
            bf16x8 af[4], bf[4];
#pragma unroll
            for (int i = 0; i < 4; ++i) {
                int rowa = wr * 64 + i * 16 + lr;
                af[i] = *(const bf16x8*)&As[rowa * 64 + (((ks << 2) | kg) ^ (rowa & 7)) * 8];
                int rowb = wc * 64 + i * 16 + lr;
                bf[i] = *(const bf16x8*)&Bs[rowb * 64 + (((ks << 2) | kg) ^ (rowb & 7)) * 8];
            }
#pragma unroll
            for (int i = 0; i < 4; ++i)
#pragma unroll
                for (int j = 0; j < 4; ++j)
                    acc[i][j] = __builtin_amdgcn_mfma_f32_16x16x32_bf16(
                        af[i], bf[j], acc[i][j], 0, 0, 0);
        }
        __syncthreads();
    }

    // ---- fused attention logits: head = n0/64 + wc ----
    int head = (n0 >> 6) + wc;
    float asv[4], adv[4];
#pragma unroll
    for (int j = 0; j < 4; ++j) {
        int cc = n0 + wc * 64 + j * 16 + lr;
        asv[j] = a_s[cc];
        adv[j] = a_d[cc];
    }
#pragma unroll
    for (int i = 0; i < 4; ++i) {
#pragma unroll
        for (int reg = 0; reg < 4; ++reg) {
            float ps = 0.f, pd = 0.f;
#pragma unroll
            for (int j = 0; j < 4; ++j) {
                ps += acc[i][j][reg] * asv[j];
                pd += acc[i][j][reg] * adv[j];
            }
#pragma unroll
            for (int d = 1; d < 16; d <<= 1) {
                ps += __shfl_xor(ps, d);
                pd += __shfl_xor(pd, d);
            }
            if (lr == 0) {
                int r = m0 + wr * 64 + i * 16 + kg * 4 + reg;
                alS[(size_t)r * HH + head] = ps;
                alD[(size_t)r * HH + head] = pd;
            }
        }
    }

#pragma unroll
    for (int i = 0; i < 4; ++i) {
        int rb = m0 + wr * 64 + i * 16 + kg * 4;
#pragma unroll
        for (int j = 0; j < 4; ++j) {
            int cc = n0 + wc * 64 + j * 16 + lr;
#pragma unroll
            for (int reg = 0; reg < 4; ++reg)
                Cb[(size_t)(rb + reg) * N + cc] = f2bf(acc[i][j][reg]);
        }
    }
}

// ---------------- layer-3 MFMA GEMM: h3[MP,40] = A[MP,512] @ W3T[48,512]^T ----
__global__ __launch_bounds__(256) void gemm3_mfma(
    const unsigned short* __restrict__ A,    // [MP][512] bf16
    const unsigned short* __restrict__ BT,   // [48][512] bf16
    float* __restrict__ C) {                 // [NN][40] f32
    __shared__ unsigned short As[128 * 64];
    __shared__ unsigned short Bs[48 * 64];
    int t = threadIdx.x;
    int wave = t >> 6, lane = t & 63;
    int m0 = blockIdx.x * 128;
    int kg = lane >> 4, lr = lane & 15;

    f32x4 acc[2][3] = {};

    for (int k0 = 0; k0 < 512; k0 += 64) {
#pragma unroll
        for (int q = 0; q < 4; ++q) {
            int c   = q * 256 + t;
            int row = c >> 3, kc = c & 7;
            int kcs = kc ^ (row & 7);
            const unsigned short* ga = A + (size_t)(m0 + row) * 512 + k0 + kcs * 8;
            unsigned short* la = &As[(size_t)(q * 256 + wave * 64) * 8];
            __builtin_amdgcn_global_load_lds(
                (const __attribute__((address_space(1))) void*)ga,
                (__attribute__((address_space(3))) void*)la, 16, 0, 0);
        }
        {
            int c   = t;
            int row = c >> 3, kc = c & 7;
            int kcs = kc ^ (row & 7);
            const unsigned short* gb = BT + (size_t)row * 512 + k0 + kcs * 8;
            unsigned short* lb = &Bs[(size_t)(wave * 64) * 8];
            __builtin_amdgcn_global_load_lds(
                (const __attribute__((address_space(1))) void*)gb,
                (__attribute__((address_space(3))) void*)lb, 16, 0, 0);
        }
        if (t < 128) {
            int c   = 256 + t;
            int row = c >> 3, kc = c & 7;
            int kcs = kc ^ (row & 7);
            const unsigned short* gb = BT + (size_t)row * 512 + k0 + kcs * 8;
            unsigned short* lb = &Bs[(size_t)(256 + wave * 64) * 8];
            __builtin_amdgcn_global_load_lds(
                (const __attribute__((address_space(1))) void*)gb,
                (__attribute__((address_space(3))) void*)lb, 16, 0, 0);
        }
        __syncthreads();
#pragma unroll
        for (int ks = 0; ks < 2; ++ks) {
            bf16x8 af[2], bf[3];
#pragma unroll
            for (int i = 0; i < 2; ++i) {
                int rowa = wave * 32 + i * 16 + lr;
                af[i] = *(const bf16x8*)&As[rowa * 64 + (((ks << 2) | kg) ^ (rowa & 7)) * 8];
            }
#pragma unroll
            for (int j = 0; j < 3; ++j) {
                int rowb = j * 16 + lr;
                bf[j] = *(const bf16x8*)&Bs[rowb * 64 + (((ks << 2) | kg) ^ (rowb & 7)) * 8];
            }
#pragma unroll
            for (int i = 0; i < 2; ++i)
#pragma unroll
                for (int j = 0; j < 3; ++j)
                    acc[i][j] = __builtin_amdgcn_mfma_f32_16x16x32_bf16(
                        af[i], bf[j], acc[i][j], 0, 0, 0);
        }
        __syncthreads();
    }

#pragma unroll
    for (int i = 0; i < 2; ++i) {
        int rb = m0 + wave * 32 + i * 16 + kg * 4;
#pragma unroll
        for (int j = 0; j < 3; ++j) {
            int cc = j * 16 + lr;
            if (cc >= F3) continue;
#pragma unroll
            for (int reg = 0; reg < 4; ++reg) {
                int r = rb + reg;
                if (r < NN) C[(size_t)r * F3 + cc] = acc[i][j][reg];
            }
        }
    }
}

// ---------------- layer-3 attention logits (F=40, C=5) ----------------
__global__ void al40_kernel(const float* __restrict__ h3, const float* __restrict__ as3,
                            const float* __restrict__ ad3, float* __restrict__ al_s,
                            float* __restrict__ al_d) {
    int n = blockIdx.x * blockDim.x + threadIdx.x;
    if (n >= NN) return;
#pragma unroll
    for (int hh = 0; hh < HH; ++hh) {
        float s = 0.f, d = 0.f;
#pragma unroll
        for (int c = 0; c < C3; ++c) {
            float v = h3[(size_t)n * F3 + hh * C3 + c];
            s += v * as3[hh * C3 + c];
            d += v * ad3[hh * C3 + c];
        }
        al_s[n * HH + hh] = s;
        al_d[n * HH + hh] = d;
    }
}

// ---------------- layer-3 attention, wave-parallel (4 nodes/block) ------------
__global__ __launch_bounds__(256) void attn3_kernel(
    const float* __restrict__ h3, const float* __restrict__ al_s,
    const float* __restrict__ al_d, const int* __restrict__ offs,
    const int* __restrict__ srcs, const float* __restrict__ b3,
    float* __restrict__ out) {
    __shared__ float alpha_sh[4][MAXE][HH];
    __shared__ int   srcs_sh[4][MAXE];
    __shared__ float idn_sh[4][HH], m_sh[4][HH], ald_sh2[4][HH];
    __shared__ float accs[4][F3];
    __shared__ float vv[4][C3];
    int w = threadIdx.x >> 6, lane = threadIdx.x & 63;
    int n = blockIdx.x * 4 + w;
    int h = lane >> 3, es = lane & 7;
    int beg = offs[n], end = offs[n + 1], deg = end - beg;

    float ald = al_d[n * HH + h];
    float m = -1e30f, den = 0.f, idn;
    if (deg <= MAXE) {
        for (int e = es; e < deg; e += 8) {
            int s = srcs[beg + e];
            if (h == 0) srcs_sh[w][e] = s;
            float sc = al_s[s * HH + h] + ald;
            sc = sc > 0.f ? sc : 0.2f * sc;
            alpha_sh[w][e][h] = sc;
            m = fmaxf(m, sc);
        }
        m = fmaxf(m, __shfl_xor(m, 1));
        m = fmaxf(m, __shfl_xor(m, 2));
        m = fmaxf(m, __shfl_xor(m, 4));
        for (int e = es; e < deg; e += 8) {
            float ex = __expf(alpha_sh[w][e][h] - m);
            den += ex;
            alpha_sh[w][e][h] = ex;
        }
        den += __shfl_xor(den, 1);
        den += __shfl_xor(den, 2);
        den += __shfl_xor(den, 4);
        idn = 1.f / (den + 1e-16f);
        if (es == 0) idn_sh[w][h] = idn;
    } else {
        for (int e = es; e < deg; e += 8) {
            int s = srcs[beg + e];
            float sc = al_s[s * HH + h] + ald;
            sc = sc > 0.f ? sc : 0.2f * sc;
            m = fmaxf(m, sc);
        }
        m = fmaxf(m, __shfl_xor(m, 1));
        m = fmaxf(m, __shfl_xor(m, 2));
        m = fmaxf(m, __shfl_xor(m, 4));
        for (int e = es; e < deg; e += 8) {
            int s = srcs[beg + e];
            float sc = al_s[s * HH + h] + ald;
            sc = sc > 0.f ? sc : 0.2f * sc;
            den += __expf(sc - m);
        }
        den += __shfl_xor(den, 1);
        den += __shfl_xor(den, 2);
        den += __shfl_xor(den, 4);
        idn = 1.f / (den + 1e-16f);
        if (es == 0) { idn_sh[w][h] = idn; m_sh[w][h] = m; ald_sh2[w][h] = ald; }
    }
    __syncthreads();

    if (lane < F3) {
        int hh = lane / C3;
        float acc = 0.f;
        if (deg <= MAXE) {
            int e = 0;
            for (; e + 4 <= deg; e += 4) {
                int s0 = srcs_sh[w][e + 0], s1 = srcs_sh[w][e + 1];
                int s2 = srcs_sh[w][e + 2], s3 = srcs_sh[w][e + 3];
                float v0 = h3[(size_t)s0 * F3 + lane];
                float v1 = h3[(size_t)s1 * F3 + lane];
                float v2 = h3[(size_t)s2 * F3 + lane];
                float v3 = h3[(size_t)s3 * F3 + lane];
                acc += alpha_sh[w][e + 0][hh] * v0 + alpha_sh[w][e + 1][hh] * v1
                     + alpha_sh[w][e + 2][hh] * v2 + alpha_sh[w][e + 3][hh] * v3;
            }
            for (; e < deg; ++e) {
                int s = srcs_sh[w][e];
                acc += alpha_sh[w][e][hh] * h3[(size_t)s * F3 + lane];
            }
        } else {
            float mm = m_sh[w][hh], aald = ald_sh2[w][hh];
            for (int e = 0; e < deg; ++e) {
                int s = srcs[beg + e];
                float sc = al_s[s * HH + hh] + aald;
                sc = sc > 0.f ? sc : 0.2f * sc;
                acc += __expf(sc - mm) * h3[(size_t)s * F3 + lane];
            }
        }
        accs[w][lane] = acc * idn_sh[w][hh];
    }
    __syncthreads();
    if (lane < C3) {
        float s = 0.f;
#pragma unroll
        for (int hh = 0; hh < HH; ++hh) s += accs[w][hh * C3 + lane];
        vv[w][lane] = s * 0.125f + b3[lane];
    }
    __syncthreads();
    if (lane < C3) {
        float mx = vv[w][0];
#pragma unroll
        for (int c = 1; c < C3; ++c) mx = fmaxf(mx, vv[w][c]);
        float se = 0.f;
#pragma unroll
        for (int c = 0; c < C3; ++c) se += __expf(vv[w][c] - mx);
        out[(size_t)n * C3 + lane] = vv[w][lane] - mx - logf(se);
    }
}

// ---------------- host launcher ----------------
extern "C" void kernel_launch(void* const* d_in, const int* in_sizes, int n_in,
                              void* d_out, int out_size, void* d_ws, size_t ws_size,
                              hipStream_t stream) {
    const float* x   = (const float*)d_in[0];
    const int*   ei  = (const int*)d_in[1];
    const float* W1  = (const float*)d_in[2];
    const float* as1 = (const float*)d_in[3];
    const float* ad1 = (const float*)d_in[4];
    const float* b1  = (const float*)d_in[5];
    const float* W2  = (const float*)d_in[6];
    const float* as2 = (const float*)d_in[7];
    const float* ad2 = (const float*)d_in[8];
    const float* b2  = (const float*)d_in[9];
    const float* W3  = (const float*)d_in[10];
    const float* as3 = (const float*)d_in[11];
    const float* ad3 = (const float*)d_in[12];
    const float* b3  = (const float*)d_in[13];
    float* out = (float*)d_out;

    // ---- workspace layout (lifetime-aliased, ~118 MB) ----
    auto au = [](size_t v) { return (v + 255) & ~(size_t)255; };
    char* p = (char*)d_ws;
    size_t szHb = au((size_t)MP * FF * 2);           // 51.25 MB
    char* r1 = p;
    unsigned short* Hb1 = (unsigned short*)r1;
    unsigned short* Hb2 = (unsigned short*)r1;
    p += szHb;
    char* r2 = p;
    unsigned short* A2   = (unsigned short*)r2;
    unsigned short* Bb16 = (unsigned short*)r2;      // alias: attn2 out
    unsigned short* W2T  = (unsigned short*)(r2 + szHb);
    p = r2 + szHb + au((size_t)FF * FF * 2);
    unsigned short* W3T = (unsigned short*)p;  p += au((size_t)48 * 512 * 2);
    float* alS  = (float*)p;  p += au((size_t)MP * HH * 4);
    float* alD  = (float*)p;  p += au((size_t)MP * HH * 4);
    float* h3   = (float*)p;  p += au((size_t)NN * F3 * 4);
    int* offs   = (int*)p;    p += au((size_t)(NN + 1) * 4);
    int* cnt    = (int*)p;    p += au((size_t)NN * 4);
    int* srcs   = (int*)p;    p += au((size_t)ETOT * 4);
    int* bsum   = (int*)p;    p += au(64 * 4);

    // ---- CSR build (dst-sorted) + prep ----
    hipMemsetAsync(cnt, 0, (size_t)NN * 4, stream);
    count_kernel<<<(ETOT + 255) / 256, 256, 0, stream>>>(ei, cnt);
    scan_blocks<<<NBLK, 1024, 0, stream>>>(cnt, offs, bsum);
    scan_add<<<NBLK, 1024, 0, stream>>>(offs, bsum);
    hipMemsetAsync(cnt, 0, (size_t)NN * 4, stream);
    scatter_kernel<<<(ETOT + 255) / 256, 256, 0, stream>>>(ei, offs, cnt, srcs);
    {
        int prep_elems = FF * FF + 48 * 512 + (MP - NN) * FF;
        prep_all<<<(prep_elems + 255) / 256, 256, 0, stream>>>(W2, W3, W2T, W3T, A2);
    }

    // ---- layer 1 ----
    gemm1_fused<<<(NN + 63) / 64, 256, 0, stream>>>(x, W1, as1, ad1, Hb1, alS, alD);
    attn_gather<<<(NN + 3) / 4, 256, 0, stream>>>(Hb1, alS, alD, offs, srcs, b1,
                                                  nullptr, A2, 1);

    // ---- layer 2: bf16 MFMA GEMM (+ fused logits), single-buffer + swizzle ---
    gemm_mfma<<<GT2, 256, 0, stream>>>(
        A2, W2T, as2, ad2, Hb2, alS, alD, FF, FF);
    attn_gather<<<(NN + 3) / 4, 256, 0, stream>>>(Hb2, alS, alD, offs, srcs, b2,
                                                  nullptr, Bb16, 1);

    // ---- layer 3 ----
    gemm3_mfma<<<MP / 128, 256, 0, stream>>>(Bb16, W3T, h3);
    al40_kernel<<<(NN + 255) / 256, 256, 0, stream>>>(h3, as3, ad3, alS, alD);
    attn3_kernel<<<NN / 4, 256, 0, stream>>>(h3, alS, alD, offs, srcs, b3, out);
}

// Round 12
// 344.828 us; speedup vs baseline: 1.0338x; 1.0338x over previous
//
#include <hip/hip_runtime.h>
#include <hip/hip_bf16.h>

#define NN    50000   // nodes
#define MP    50048   // padded to 128*391 for MFMA GEMM
#define E0C   400000  // raw edges
#define ETOT  450000  // + self loops
#define HH    8
#define FF    512     // H*C layers 1-2
#define F3    40      // H*C3 layer 3
#define C3    5
#define MAXE  128     // LDS alpha-cache capacity (deg ~ Poisson(8)+1)
#define NBLK  ((NN + 1023) / 1024)   // 49 scan blocks
#define MT2   (MP / 128)             // 391 m-tiles layer-2 gemm
#define GT2   (MT2 * 4)              // 1564 blocks

typedef __attribute__((ext_vector_type(8))) short bf16x8;
typedef __attribute__((ext_vector_type(8))) short s16x8;
typedef __attribute__((ext_vector_type(4))) float f32x4;

__device__ inline unsigned short f2bf(float f) {
    union { float f; unsigned int u; } v; v.f = f;
    unsigned int r = v.u + 0x7FFF + ((v.u >> 16) & 1);
    return (unsigned short)(r >> 16);
}
__device__ inline float bf2f(unsigned short u) {
    union { unsigned int i; float f; } v; v.i = ((unsigned int)u) << 16;
    return v.f;
}

// ---------------- CSR build ----------------
__global__ void count_kernel(const int* __restrict__ ei, int* __restrict__ cnt) {
    int e = blockIdx.x * blockDim.x + threadIdx.x;
    if (e >= ETOT) return;
    int dst = (e < E0C) ? ei[E0C + e] : (e - E0C);
    atomicAdd(&cnt[dst], 1);
}

// scan_blocks also re-zeroes cnt after reading (cnt is reused as the scatter
// cursor array) -> saves a memset dispatch.
__global__ __launch_bounds__(1024) void scan_blocks(int* __restrict__ cnt,
                                                    int* __restrict__ offs,
                                                    int* __restrict__ bsum) {
    __shared__ int s[1024];
    int tid = threadIdx.x;
    int i = blockIdx.x * 1024 + tid;
    int v = (i < NN) ? cnt[i] : 0;
    if (i < NN) cnt[i] = 0;
    s[tid] = v;
    __syncthreads();
    for (int d = 1; d < 1024; d <<= 1) {
        int add = (tid >= d) ? s[tid - d] : 0;
        __syncthreads();
        s[tid] += add;
        __syncthreads();
    }
    if (i < NN) offs[i + 1] = s[tid];
    if (tid == 1023) bsum[blockIdx.x] = s[1023];
}

// scan_add with integrated carry: wave 0 sums bsum[0..blockIdx.x-1] in-kernel.
__global__ __launch_bounds__(1024) void scan_add(int* __restrict__ offs,
                                                 const int* __restrict__ bsum) {
    __shared__ int pref;
    int tid = threadIdx.x;
    if (tid < 64) {
        int v = (tid < blockIdx.x) ? bsum[tid] : 0;   // NBLK=49 <= 64
#pragma unroll
        for (int d = 32; d; d >>= 1) v += __shfl_xor(v, d);
        if (tid == 0) pref = v;
    }
    __syncthreads();
    int i = blockIdx.x * 1024 + tid;
    if (i < NN) offs[i + 1] += pref;
    if (i == 0) offs[0] = 0;
}

__global__ void scatter_kernel(const int* __restrict__ ei, const int* __restrict__ offs,
                               int* __restrict__ cur, int* __restrict__ srcs) {
    int e = blockIdx.x * blockDim.x + threadIdx.x;
    if (e >= ETOT) return;
    int src, dst;
    if (e < E0C) { src = ei[e]; dst = ei[E0C + e]; }
    else         { src = dst = e - E0C; }
    int pos = offs[dst] + atomicAdd(&cur[dst], 1);
    srcs[pos] = src;
}

// ---------------- fused prep: W2T + W3T + A2 tail zero (one dispatch) --------
__global__ void prep_all(const float* __restrict__ W2, const float* __restrict__ W3,
                         unsigned short* __restrict__ W2T, unsigned short* __restrict__ W3T,
                         unsigned short* __restrict__ A2) {
    int i = blockIdx.x * blockDim.x + threadIdx.x;
    if (i < FF * FF) {
        int n = i >> 9, k = i & 511;
        W2T[i] = f2bf(W2[k * FF + n]);
        return;
    }
    int j = i - FF * FF;
    if (j < 48 * 512) {
        int n = j >> 9, k = j & 511;
        W3T[j] = (n < F3) ? f2bf(W3[k * F3 + n]) : 0;
        return;
    }
    int l = j - 48 * 512;
    if (l < (MP - NN) * FF) A2[(size_t)NN * FF + l] = 0;
}

// ---------------- layer 1 GEMM (K=12) fused with logits, 64 nodes/block ------
__global__ __launch_bounds__(256) void gemm1_fused(
    const float* __restrict__ x, const float* __restrict__ W1,
    const float* __restrict__ as1, const float* __restrict__ ad1,
    unsigned short* __restrict__ hb, float* __restrict__ al_s,
    float* __restrict__ al_d) {
    __shared__ float xs[64 * 12];
    int t = threadIdx.x;
    int n0 = blockIdx.x * 64;
    int nvalid = NN - n0; if (nvalid > 64) nvalid = 64;

    for (int j = t; j < nvalid * 12; j += 256) xs[j] = x[(size_t)n0 * 12 + j];
    __syncthreads();

    int f = t * 2;
    float w0[12], w1[12];
#pragma unroll
    for (int k = 0; k < 12; ++k) {
        float2 wv = *(const float2*)&W1[k * FF + f];
        w0[k] = wv.x; w1[k] = wv.y;
    }
    float2 asv = *(const float2*)&as1[f];
    float2 adv = *(const float2*)&ad1[f];
    int head = t >> 5;

    for (int ni = 0; ni < nvalid; ++ni) {
        const float* xp = &xs[ni * 12];
        float4 xa = *(const float4*)xp;
        float4 xb = *(const float4*)(xp + 4);
        float4 xc = *(const float4*)(xp + 8);
        float xv[12] = {xa.x, xa.y, xa.z, xa.w, xb.x, xb.y, xb.z, xb.w,
                        xc.x, xc.y, xc.z, xc.w};
        float h0 = 0.f, h1 = 0.f;
#pragma unroll
        for (int k = 0; k < 12; ++k) { h0 += xv[k] * w0[k]; h1 += xv[k] * w1[k]; }
        unsigned int u = ((unsigned int)f2bf(h1) << 16) | f2bf(h0);
        *(unsigned int*)&hb[(size_t)(n0 + ni) * FF + f] = u;
        float ps = h0 * asv.x + h1 * asv.y;
        float pd = h0 * adv.x + h1 * adv.y;
#pragma unroll
        for (int d = 1; d < 32; d <<= 1) {
            ps += __shfl_xor(ps, d);
            pd += __shfl_xor(pd, d);
        }
        if ((t & 31) == 0) {
            al_s[(size_t)(n0 + ni) * HH + head] = ps;
            al_d[(size_t)(n0 + ni) * HH + head] = pd;
        }
    }
}

// ---------------- attention aggregate: ONE WAVE PER NODE, bf16 gather ----------
__global__ __launch_bounds__(256) void attn_gather(
    const unsigned short* __restrict__ Hb,   // [*,FF] bf16
    const float* __restrict__ alS, const float* __restrict__ alD,
    const int* __restrict__ offs, const int* __restrict__ srcs,
    const float* __restrict__ bias,
    float* __restrict__ out_f32, unsigned short* __restrict__ out_b16, int relu) {
    __shared__ float alpha_sh[4][MAXE][HH];
    __shared__ int   srcs_sh[4][MAXE];
    int w = threadIdx.x >> 6, lane = threadIdx.x & 63;
    int n = blockIdx.x * 4 + w;
    if (n >= NN) return;
    int h = lane >> 3, es = lane & 7;
    int beg = offs[n], end = offs[n + 1], deg = end - beg;

    float ald = alD[n * HH + h];
    float m = -1e30f, den = 0.f, idn;

    if (deg <= MAXE) {
        for (int e = es; e < deg; e += 8) {
            int s = srcs[beg + e];
            if (h == 0) srcs_sh[w][e] = s;
            float sc = alS[s * HH + h] + ald;
            sc = sc > 0.f ? sc : 0.2f * sc;
            alpha_sh[w][e][h] = sc;
            m = fmaxf(m, sc);
        }
        m = fmaxf(m, __shfl_xor(m, 1));
        m = fmaxf(m, __shfl_xor(m, 2));
        m = fmaxf(m, __shfl_xor(m, 4));
        for (int e = es; e < deg; e += 8) {
            float ex = __expf(alpha_sh[w][e][h] - m);
            den += ex;
            alpha_sh[w][e][h] = ex;
        }
        den += __shfl_xor(den, 1);
        den += __shfl_xor(den, 2);
        den += __shfl_xor(den, 4);
        idn = 1.f / (den + 1e-16f);
    } else {
        for (int e = es; e < deg; e += 8) {
            int s = srcs[beg + e];
            float sc = alS[s * HH + h] + ald;
            sc = sc > 0.f ? sc : 0.2f * sc;
            m = fmaxf(m, sc);
        }
        m = fmaxf(m, __shfl_xor(m, 1));
        m = fmaxf(m, __shfl_xor(m, 2));
        m = fmaxf(m, __shfl_xor(m, 4));
        for (int e = es; e < deg; e += 8) {
            int s = srcs[beg + e];
            float sc = alS[s * HH + h] + ald;
            sc = sc > 0.f ? sc : 0.2f * sc;
            den += __expf(sc - m);
        }
        den += __shfl_xor(den, 1);
        den += __shfl_xor(den, 2);
        den += __shfl_xor(den, 4);
        idn = 1.f / (den + 1e-16f);
    }

    int f0 = lane * 8;
    float acc[8] = {};
    if (deg <= MAXE) {
        int e = 0;
        for (; e + 4 <= deg; e += 4) {
            int s0 = srcs_sh[w][e + 0], s1 = srcs_sh[w][e + 1];
            int s2 = srcs_sh[w][e + 2], s3 = srcs_sh[w][e + 3];
            bf16x8 v0 = *(const bf16x8*)&Hb[(size_t)s0 * FF + f0];
            bf16x8 v1 = *(const bf16x8*)&Hb[(size_t)s1 * FF + f0];
            bf16x8 v2 = *(const bf16x8*)&Hb[(size_t)s2 * FF + f0];
            bf16x8 v3 = *(const bf16x8*)&Hb[(size_t)s3 * FF + f0];
            float a0 = alpha_sh[w][e + 0][h], a1 = alpha_sh[w][e + 1][h];
            float a2 = alpha_sh[w][e + 2][h], a3 = alpha_sh[w][e + 3][h];
#pragma unroll
            for (int k = 0; k < 8; ++k) {
                acc[k] += a0 * bf2f((unsigned short)v0[k]);
                acc[k] += a1 * bf2f((unsigned short)v1[k]);
                acc[k] += a2 * bf2f((unsigned short)v2[k]);
                acc[k] += a3 * bf2f((unsigned short)v3[k]);
            }
        }
        for (; e < deg; ++e) {
            int s = srcs_sh[w][e];
            float a = alpha_sh[w][e][h];
            bf16x8 v = *(const bf16x8*)&Hb[(size_t)s * FF + f0];
#pragma unroll
            for (int k = 0; k < 8; ++k)
                acc[k] += a * bf2f((unsigned short)v[k]);
        }
#pragma unroll
        for (int k = 0; k < 8; ++k) acc[k] *= idn;
    } else {
        for (int e = 0; e < deg; ++e) {
            int s = srcs[beg + e];
            float sc = alS[s * HH + h] + ald;
            sc = sc > 0.f ? sc : 0.2f * sc;
            float a = __expf(sc - m) * idn;
            bf16x8 v = *(const bf16x8*)&Hb[(size_t)s * FF + f0];
#pragma unroll
            for (int k = 0; k < 8; ++k)
                acc[k] += a * bf2f((unsigned short)v[k]);
        }
    }
    float4 b0 = *(const float4*)&bias[f0];
    float4 b1 = *(const float4*)&bias[f0 + 4];
    float bv[8] = {b0.x, b0.y, b0.z, b0.w, b1.x, b1.y, b1.z, b1.w};
    float vv[8];
#pragma unroll
    for (int k = 0; k < 8; ++k) {
        float t = acc[k] + bv[k];
        vv[k] = relu ? fmaxf(t, 0.f) : t;
    }
    if (out_f32) {
        float4 o0 = {vv[0], vv[1], vv[2], vv[3]};
        float4 o1 = {vv[4], vv[5], vv[6], vv[7]};
        *(float4*)&out_f32[(size_t)n * FF + f0] = o0;
        *(float4*)&out_f32[(size_t)n * FF + f0 + 4] = o1;
    }
    if (out_b16) {
        s16x8 ov;
#pragma unroll
        for (int k = 0; k < 8; ++k) ov[k] = (short)f2bf(vv[k]);
        *(s16x8*)&out_b16[(size_t)n * FF + f0] = ov;
    }
}

// ---------------- bf16 MFMA GEMM + fused logits, bf16 output (2-phase dbuf) ---
// R10's measured-best variant: double-buffered LDS + L2-affinity swizzle.
__global__ __launch_bounds__(256) void gemm_mfma(
    const unsigned short* __restrict__ A,   // [MP][K] bf16
    const unsigned short* __restrict__ BT,  // [N][K]  bf16
    const float* __restrict__ a_s, const float* __restrict__ a_d,  // [N]
    unsigned short* __restrict__ Cb,        // [MP][N] bf16
    float* __restrict__ alS, float* __restrict__ alD,              // [MP][HH]
    int N, int K) {
    __shared__ unsigned short As[2][128 * 64];
    __shared__ unsigned short Bs[2][128 * 64];
    int t = threadIdx.x;
    int wave = t >> 6, lane = t & 63;
    int wr = wave >> 1, wc = wave & 1;

    // bijective bid -> (mt, nt): same-m blocks 8 apart in dispatch order.
    int bid = blockIdx.x;
    int mt, nt;
    if (bid < (MT2 / 8) * 32) {
        int g = bid >> 5, r = bid & 31;
        mt = g * 8 + (r & 7);
        nt = r >> 3;
    } else {
        int t2 = bid - (MT2 / 8) * 32;
        mt = (MT2 / 8) * 8 + (t2 >> 2);
        nt = t2 & 3;
    }
    int m0 = mt * 128, n0 = nt * 128;

    f32x4 acc[4][4] = {};
    int kg = lane >> 4;
    int lr = lane & 15;

    auto STAGE = [&](int buf, int k0) {
#pragma unroll
        for (int q = 0; q < 4; ++q) {
            int c   = q * 256 + t;
            int row = c >> 3, kc = c & 7;
            int kcs = kc ^ (row & 7);
            const unsigned short* ga = A + (size_t)(m0 + row) * K + k0 + kcs * 8;
            const unsigned short* gb = BT + (size_t)(n0 + row) * K + k0 + kcs * 8;
            unsigned short* la = &As[buf][(size_t)(q * 256 + wave * 64) * 8];
            unsigned short* lb = &Bs[buf][(size_t)(q * 256 + wave * 64) * 8];
            __builtin_amdgcn_global_load_lds(
                (const __attribute__((address_space(1))) void*)ga,
                (__attribute__((address_space(3))) void*)la, 16, 0, 0);
            __builtin_amdgcn_global_load_lds(
                (const __attribute__((address_space(1))) void*)gb,
                (__attribute__((address_space(3))) void*)lb, 16, 0, 0);
        }
    };

    const int NT = K / 64;
    STAGE(0, 0);
    __syncthreads();
    int cur = 0;
    for (int kt = 0; kt < NT; ++kt) {
        if (kt + 1 < NT) STAGE(cur ^ 1, (kt + 1) * 64);
        const unsigned short* Ac = As[cur];
        const unsigned short* Bc = Bs[cur];
#pragma unroll
        for (int ks = 0; ks < 2; ++ks) {
            bf16x8 af[4], bf[4];
#pragma unroll
            for (int i = 0; i < 4; ++i) {
                int rowa = wr * 64 + i * 16 + lr;
                af[i] = *(const bf16x8*)&Ac[rowa * 64 + (((ks << 2) | kg) ^ (rowa & 7)) * 8];
                int rowb = wc * 64 + i * 16 + lr;
                bf[i] = *(const bf16x8*)&Bc[rowb * 64 + (((ks << 2) | kg) ^ (rowb & 7)) * 8];
            }
#pragma unroll
            for (int i = 0; i < 4; ++i)
#pragma unroll
                for (int j = 0; j < 4; ++j)
                    acc[i][j] = __builtin_amdgcn_mfma_f32_16x16x32_bf16(
                        af[i], bf[j], acc[i][j], 0, 0, 0);
        }
        __syncthreads();   // drains prefetch vmcnt + compute lgkm; buffers swap
        cur ^= 1;
    }

    // ---- fused attention logits: head = n0/64 + wc ----
    int head = (n0 >> 6) + wc;
    float asv[4], adv[4];
#pragma unroll
    for (int j = 0; j < 4; ++j) {
        int cc = n0 + wc * 64 + j * 16 + lr;
        asv[j] = a_s[cc];
        adv[j] = a_d[cc];
    }
#pragma unroll
    for (int i = 0; i < 4; ++i) {
#pragma unroll
        for (int reg = 0; reg < 4; ++reg) {
            float ps = 0.f, pd = 0.f;
#pragma unroll
            for (int j = 0; j < 4; ++j) {
                ps += acc[i][j][reg] * asv[j];
                pd += acc[i][j][reg] * adv[j];
            }
#pragma unroll
            for (int d = 1; d < 16; d <<= 1) {
                ps += __shfl_xor(ps, d);
                pd += __shfl_xor(pd, d);
            }
            if (lr == 0) {
                int r = m0 + wr * 64 + i * 16 + kg * 4 + reg;
                alS[(size_t)r * HH + head] = ps;
                alD[(size_t)r * HH + head] = pd;
            }
        }
    }

#pragma unroll
    for (int i = 0; i < 4; ++i) {
        int rb = m0 + wr * 64 + i * 16 + kg * 4;
#pragma unroll
        for (int j = 0; j < 4; ++j) {
            int cc = n0 + wc * 64 + j * 16 + lr;
#pragma unroll
            for (int reg = 0; reg < 4; ++reg)
                Cb[(size_t)(rb + reg) * N + cc] = f2bf(acc[i][j][reg]);
        }
    }
}

// ---------------- layer-3 MFMA GEMM: h3[MP,40] = A[MP,512] @ W3T[48,512]^T ----
__global__ __launch_bounds__(256) void gemm3_mfma(
    const unsigned short* __restrict__ A,    // [MP][512] bf16
    const unsigned short* __restrict__ BT,   // [48][512] bf16
    float* __restrict__ C) {                 // [NN][40] f32
    __shared__ unsigned short As[128 * 64];
    __shared__ unsigned short Bs[48 * 64];
    int t = threadIdx.x;
    int wave = t >> 6, lane = t & 63;
    int m0 = blockIdx.x * 128;
    int kg = lane >> 4, lr = lane & 15;

    f32x4 acc[2][3] = {};

    for (int k0 = 0; k0 < 512; k0 += 64) {
#pragma unroll
        for (int q = 0; q < 4; ++q) {
            int c   = q * 256 + t;
            int row = c >> 3, kc = c & 7;
            int kcs = kc ^ (row & 7);
            const unsigned short* ga = A + (size_t)(m0 + row) * 512 + k0 + kcs * 8;
            unsigned short* la = &As[(size_t)(q * 256 + wave * 64) * 8];
            __builtin_amdgcn_global_load_lds(
                (const __attribute__((address_space(1))) void*)ga,
                (__attribute__((address_space(3))) void*)la, 16, 0, 0);
        }
        {
            int c   = t;
            int row = c >> 3, kc = c & 7;
            int kcs = kc ^ (row & 7);
            const unsigned short* gb = BT + (size_t)row * 512 + k0 + kcs * 8;
            unsigned short* lb = &Bs[(size_t)(wave * 64) * 8];
            __builtin_amdgcn_global_load_lds(
                (const __attribute__((address_space(1))) void*)gb,
                (__attribute__((address_space(3))) void*)lb, 16, 0, 0);
        }
        if (t < 128) {
            int c   = 256 + t;
            int row = c >> 3, kc = c & 7;
            int kcs = kc ^ (row & 7);
            const unsigned short* gb = BT + (size_t)row * 512 + k0 + kcs * 8;
            unsigned short* lb = &Bs[(size_t)(256 + wave * 64) * 8];
            __builtin_amdgcn_global_load_lds(
                (const __attribute__((address_space(1))) void*)gb,
                (__attribute__((address_space(3))) void*)lb, 16, 0, 0);
        }
        __syncthreads();
#pragma unroll
        for (int ks = 0; ks < 2; ++ks) {
            bf16x8 af[2], bf[3];
#pragma unroll
            for (int i = 0; i < 2; ++i) {
                int rowa = wave * 32 + i * 16 + lr;
                af[i] = *(const bf16x8*)&As[rowa * 64 + (((ks << 2) | kg) ^ (rowa & 7)) * 8];
            }
#pragma unroll
            for (int j = 0; j < 3; ++j) {
                int rowb = j * 16 + lr;
                bf[j] = *(const bf16x8*)&Bs[rowb * 64 + (((ks << 2) | kg) ^ (rowb & 7)) * 8];
            }
#pragma unroll
            for (int i = 0; i < 2; ++i)
#pragma unroll
                for (int j = 0; j < 3; ++j)
                    acc[i][j] = __builtin_amdgcn_mfma_f32_16x16x32_bf16(
                        af[i], bf[j], acc[i][j], 0, 0, 0);
        }
        __syncthreads();
    }

#pragma unroll
    for (int i = 0; i < 2; ++i) {
        int rb = m0 + wave * 32 + i * 16 + kg * 4;
#pragma unroll
        for (int j = 0; j < 3; ++j) {
            int cc = j * 16 + lr;
            if (cc >= F3) continue;
#pragma unroll
            for (int reg = 0; reg < 4; ++reg) {
                int r = rb + reg;
                if (r < NN) C[(size_t)r * F3 + cc] = acc[i][j][reg];
            }
        }
    }
}

// ---------------- layer-3 attention logits (F=40, C=5) ----------------
__global__ void al40_kernel(const float* __restrict__ h3, const float* __restrict__ as3,
                            const float* __restrict__ ad3, float* __restrict__ al_s,
                            float* __restrict__ al_d) {
    int n = blockIdx.x * blockDim.x + threadIdx.x;
    if (n >= NN) return;
#pragma unroll
    for (int hh = 0; hh < HH; ++hh) {
        float s = 0.f, d = 0.f;
#pragma unroll
        for (int c = 0; c < C3; ++c) {
            float v = h3[(size_t)n * F3 + hh * C3 + c];
            s += v * as3[hh * C3 + c];
            d += v * ad3[hh * C3 + c];
        }
        al_s[n * HH + hh] = s;
        al_d[n * HH + hh] = d;
    }
}

// ---------------- layer-3 attention, wave-parallel (4 nodes/block) ------------
__global__ __launch_bounds__(256) void attn3_kernel(
    const float* __restrict__ h3, const float* __restrict__ al_s,
    const float* __restrict__ al_d, const int* __restrict__ offs,
    const int* __restrict__ srcs, const float* __restrict__ b3,
    float* __restrict__ out) {
    __shared__ float alpha_sh[4][MAXE][HH];
    __shared__ int   srcs_sh[4][MAXE];
    __shared__ float idn_sh[4][HH], m_sh[4][HH], ald_sh2[4][HH];
    __shared__ float accs[4][F3];
    __shared__ float vv[4][C3];
    int w = threadIdx.x >> 6, lane = threadIdx.x & 63;
    int n = blockIdx.x * 4 + w;
    int h = lane >> 3, es = lane & 7;
    int beg = offs[n], end = offs[n + 1], deg = end - beg;

    float ald = al_d[n * HH + h];
    float m = -1e30f, den = 0.f, idn;
    if (deg <= MAXE) {
        for (int e = es; e < deg; e += 8) {
            int s = srcs[beg + e];
            if (h == 0) srcs_sh[w][e] = s;
            float sc = al_s[s * HH + h] + ald;
            sc = sc > 0.f ? sc : 0.2f * sc;
            alpha_sh[w][e][h] = sc;
            m = fmaxf(m, sc);
        }
        m = fmaxf(m, __shfl_xor(m, 1));
        m = fmaxf(m, __shfl_xor(m, 2));
        m = fmaxf(m, __shfl_xor(m, 4));
        for (int e = es; e < deg; e += 8) {
            float ex = __expf(alpha_sh[w][e][h] - m);
            den += ex;
            alpha_sh[w][e][h] = ex;
        }
        den += __shfl_xor(den, 1);
        den += __shfl_xor(den, 2);
        den += __shfl_xor(den, 4);
        idn = 1.f / (den + 1e-16f);
        if (es == 0) idn_sh[w][h] = idn;
    } else {
        for (int e = es; e < deg; e += 8) {
            int s = srcs[beg + e];
            float sc = al_s[s * HH + h] + ald;
            sc = sc > 0.f ? sc : 0.2f * sc;
            m = fmaxf(m, sc);
        }
        m = fmaxf(m, __shfl_xor(m, 1));
        m = fmaxf(m, __shfl_xor(m, 2));
        m = fmaxf(m, __shfl_xor(m, 4));
        for (int e = es; e < deg; e += 8) {
            int s = srcs[beg + e];
            float sc = al_s[s * HH + h] + ald;
            sc = sc > 0.f ? sc : 0.2f * sc;
            den += __expf(sc - m);
        }
        den += __shfl_xor(den, 1);
        den += __shfl_xor(den, 2);
        den += __shfl_xor(den, 4);
        idn = 1.f / (den + 1e-16f);
        if (es == 0) { idn_sh[w][h] = idn; m_sh[w][h] = m; ald_sh2[w][h] = ald; }
    }
    __syncthreads();

    if (lane < F3) {
        int hh = lane / C3;
        float acc = 0.f;
        if (deg <= MAXE) {
            int e = 0;
            for (; e + 4 <= deg; e += 4) {
                int s0 = srcs_sh[w][e + 0], s1 = srcs_sh[w][e + 1];
                int s2 = srcs_sh[w][e + 2], s3 = srcs_sh[w][e + 3];
                float v0 = h3[(size_t)s0 * F3 + lane];
                float v1 = h3[(size_t)s1 * F3 + lane];
                float v2 = h3[(size_t)s2 * F3 + lane];
                float v3 = h3[(size_t)s3 * F3 + lane];
                acc += alpha_sh[w][e + 0][hh] * v0 + alpha_sh[w][e + 1][hh] * v1
                     + alpha_sh[w][e + 2][hh] * v2 + alpha_sh[w][e + 3][hh] * v3;
            }
            for (; e < deg; ++e) {
                int s = srcs_sh[w][e];
                acc += alpha_sh[w][e][hh] * h3[(size_t)s * F3 + lane];
            }
        } else {
            float mm = m_sh[w][hh], aald = ald_sh2[w][hh];
            for (int e = 0; e < deg; ++e) {
                int s = srcs[beg + e];
                float sc = al_s[s * HH + hh] + aald;
                sc = sc > 0.f ? sc : 0.2f * sc;
                acc += __expf(sc - mm) * h3[(size_t)s * F3 + lane];
            }
        }
        accs[w][lane] = acc * idn_sh[w][hh];
    }
    __syncthreads();
    if (lane < C3) {
        float s = 0.f;
#pragma unroll
        for (int hh = 0; hh < HH; ++hh) s += accs[w][hh * C3 + lane];
        vv[w][lane] = s * 0.125f + b3[lane];
    }
    __syncthreads();
    if (lane < C3) {
        float mx = vv[w][0];
#pragma unroll
        for (int c = 1; c < C3; ++c) mx = fmaxf(mx, vv[w][c]);
        float se = 0.f;
#pragma unroll
        for (int c = 0; c < C3; ++c) se += __expf(vv[w][c] - mx);
        out[(size_t)n * C3 + lane] = vv[w][lane] - mx - logf(se);
    }
}

// ---------------- host launcher ----------------
extern "C" void kernel_launch(void* const* d_in, const int* in_sizes, int n_in,
                              void* d_out, int out_size, void* d_ws, size_t ws_size,
                              hipStream_t stream) {
    const float* x   = (const float*)d_in[0];
    const int*   ei  = (const int*)d_in[1];
    const float* W1  = (const float*)d_in[2];
    const float* as1 = (const float*)d_in[3];
    const float* ad1 = (const float*)d_in[4];
    const float* b1  = (const float*)d_in[5];
    const float* W2  = (const float*)d_in[6];
    const float* as2 = (const float*)d_in[7];
    const float* ad2 = (const float*)d_in[8];
    const float* b2  = (const float*)d_in[9];
    const float* W3  = (const float*)d_in[10];
    const float* as3 = (const float*)d_in[11];
    const float* ad3 = (const float*)d_in[12];
    const float* b3  = (const float*)d_in[13];
    float* out = (float*)d_out;

    // ---- workspace layout (lifetime-aliased, ~118 MB) ----
    auto au = [](size_t v) { return (v + 255) & ~(size_t)255; };
    char* p = (char*)d_ws;
    size_t szHb = au((size_t)MP * FF * 2);           // 51.25 MB
    char* r1 = p;
    unsigned short* Hb1 = (unsigned short*)r1;
    unsigned short* Hb2 = (unsigned short*)r1;
    p += szHb;
    char* r2 = p;
    unsigned short* A2   = (unsigned short*)r2;
    unsigned short* Bb16 = (unsigned short*)r2;      // alias: attn2 out
    unsigned short* W2T  = (unsigned short*)(r2 + szHb);
    p = r2 + szHb + au((size_t)FF * FF * 2);
    unsigned short* W3T = (unsigned short*)p;  p += au((size_t)48 * 512 * 2);
    float* alS  = (float*)p;  p += au((size_t)MP * HH * 4);
    float* alD  = (float*)p;  p += au((size_t)MP * HH * 4);
    float* h3   = (float*)p;  p += au((size_t)NN * F3 * 4);
    int* offs   = (int*)p;    p += au((size_t)(NN + 1) * 4);
    int* cnt    = (int*)p;    p += au((size_t)NN * 4);
    int* srcs   = (int*)p;    p += au((size_t)ETOT * 4);
    int* bsum   = (int*)p;    p += au(64 * 4);

    // ---- CSR build (dst-sorted) + prep ----
    hipMemsetAsync(cnt, 0, (size_t)NN * 4, stream);
    count_kernel<<<(ETOT + 255) / 256, 256, 0, stream>>>(ei, cnt);
    scan_blocks<<<NBLK, 1024, 0, stream>>>(cnt, offs, bsum);  // also re-zeros cnt
    scan_add<<<NBLK, 1024, 0, stream>>>(offs, bsum);
    scatter_kernel<<<(ETOT + 255) / 256, 256, 0, stream>>>(ei, offs, cnt, srcs);
    {
        int prep_elems = FF * FF + 48 * 512 + (MP - NN) * FF;
        prep_all<<<(prep_elems + 255) / 256, 256, 0, stream>>>(W2, W3, W2T, W3T, A2);
    }

    // ---- layer 1 ----
    gemm1_fused<<<(NN + 63) / 64, 256, 0, stream>>>(x, W1, as1, ad1, Hb1, alS, alD);
    attn_gather<<<(NN + 3) / 4, 256, 0, stream>>>(Hb1, alS, alD, offs, srcs, b1,
                                                  nullptr, A2, 1);

    // ---- layer 2: bf16 MFMA GEMM (+ fused logits), dbuf + L2-affinity swizzle
    gemm_mfma<<<GT2, 256, 0, stream>>>(
        A2, W2T, as2, ad2, Hb2, alS, alD, FF, FF);
    attn_gather<<<(NN + 3) / 4, 256, 0, stream>>>(Hb2, alS, alD, offs, srcs, b2,
                                                  nullptr, Bb16, 1);

    // ---- layer 3 ----
    gemm3_mfma<<<MP / 128, 256, 0, stream>>>(Bb16, W3T, h3);
    al40_kernel<<<(NN + 255) / 256, 256, 0, stream>>>(h3, as3, ad3, alS, alD);
    attn3_kernel<<<NN / 4, 256, 0, stream>>>(h3, alS, alD, offs, srcs, b3, out);
}

// Round 13
// 335.404 us; speedup vs baseline: 1.0628x; 1.0281x over previous
//
#include <hip/hip_runtime.h>
#include <hip/hip_bf16.h>

#define NN    50000   // nodes
#define MP    50048   // padded to 128*391 for MFMA GEMM
#define E0C   400000  // raw edges
#define ETOT  450000  // + self loops
#define HH    8
#define FF    512     // H*C layers 1-2
#define F3    40      // H*C3 layer 3
#define C3    5
#define MAXE  128     // LDS alpha-cache capacity (deg ~ Poisson(8)+1)
#define NBLK  ((NN + 1023) / 1024)   // 49 scan blocks
#define MT2   (MP / 128)             // 391 m-tiles layer-2 gemm
#define GT2   (MT2 * 4)              // 1564 blocks

typedef __attribute__((ext_vector_type(8))) short bf16x8;
typedef __attribute__((ext_vector_type(8))) short s16x8;
typedef __attribute__((ext_vector_type(4))) float f32x4;

__device__ inline unsigned short f2bf(float f) {
    union { float f; unsigned int u; } v; v.f = f;
    unsigned int r = v.u + 0x7FFF + ((v.u >> 16) & 1);
    return (unsigned short)(r >> 16);
}
__device__ inline float bf2f(unsigned short u) {
    union { unsigned int i; float f; } v; v.i = ((unsigned int)u) << 16;
    return v.f;
}

// ---------------- CSR build ----------------
__global__ void count_kernel(const int* __restrict__ ei, int* __restrict__ cnt) {
    int e = blockIdx.x * blockDim.x + threadIdx.x;
    if (e >= ETOT) return;
    int dst = (e < E0C) ? ei[E0C + e] : (e - E0C);
    atomicAdd(&cnt[dst], 1);
}

// scan_blocks also re-zeroes cnt after reading (cnt reused as scatter cursor).
__global__ __launch_bounds__(1024) void scan_blocks(int* __restrict__ cnt,
                                                    int* __restrict__ offs,
                                                    int* __restrict__ bsum) {
    __shared__ int s[1024];
    int tid = threadIdx.x;
    int i = blockIdx.x * 1024 + tid;
    int v = (i < NN) ? cnt[i] : 0;
    if (i < NN) cnt[i] = 0;
    s[tid] = v;
    __syncthreads();
    for (int d = 1; d < 1024; d <<= 1) {
        int add = (tid >= d) ? s[tid - d] : 0;
        __syncthreads();
        s[tid] += add;
        __syncthreads();
    }
    if (i < NN) offs[i + 1] = s[tid];
    if (tid == 1023) bsum[blockIdx.x] = s[1023];
}

// scan_add with integrated carry: wave 0 sums bsum[0..blockIdx.x-1] in-kernel.
__global__ __launch_bounds__(1024) void scan_add(int* __restrict__ offs,
                                                 const int* __restrict__ bsum) {
    __shared__ int pref;
    int tid = threadIdx.x;
    if (tid < 64) {
        int v = (tid < blockIdx.x) ? bsum[tid] : 0;   // NBLK=49 <= 64
#pragma unroll
        for (int d = 32; d; d >>= 1) v += __shfl_xor(v, d);
        if (tid == 0) pref = v;
    }
    __syncthreads();
    int i = blockIdx.x * 1024 + tid;
    if (i < NN) offs[i + 1] += pref;
    if (i == 0) offs[0] = 0;
}

__global__ void scatter_kernel(const int* __restrict__ ei, const int* __restrict__ offs,
                               int* __restrict__ cur, int* __restrict__ srcs) {
    int e = blockIdx.x * blockDim.x + threadIdx.x;
    if (e >= ETOT) return;
    int src, dst;
    if (e < E0C) { src = ei[e]; dst = ei[E0C + e]; }
    else         { src = dst = e - E0C; }
    int pos = offs[dst] + atomicAdd(&cur[dst], 1);
    srcs[pos] = src;
}

// ---------------- fused prep: W2T, W3T, A2 tail, W1T (K-pad 64), xb ----------
__global__ void prep_all(const float* __restrict__ W2, const float* __restrict__ W3,
                         const float* __restrict__ W1, const float* __restrict__ x,
                         unsigned short* __restrict__ W2T, unsigned short* __restrict__ W3T,
                         unsigned short* __restrict__ W1T, unsigned short* __restrict__ xb,
                         unsigned short* __restrict__ A2) {
    int i = blockIdx.x * blockDim.x + threadIdx.x;
    if (i < FF * FF) {
        int n = i >> 9, k = i & 511;
        W2T[i] = f2bf(W2[k * FF + n]);
        return;
    }
    i -= FF * FF;
    if (i < 48 * 512) {
        int n = i >> 9, k = i & 511;
        W3T[i] = (n < F3) ? f2bf(W3[k * F3 + n]) : 0;
        return;
    }
    i -= 48 * 512;
    if (i < (MP - NN) * FF) {
        A2[(size_t)NN * FF + i] = 0;
        return;
    }
    i -= (MP - NN) * FF;
    if (i < 512 * 64) {
        int n = i >> 6, k = i & 63;
        W1T[i] = (k < 12) ? f2bf(W1[k * FF + n]) : 0;
        return;
    }
    i -= 512 * 64;
    if (i < MP * 64) {
        int r = i >> 6, k = i & 63;
        xb[i] = (r < NN && k < 12) ? f2bf(x[r * 12 + k]) : 0;
    }
}

// ---------------- attention aggregate: ONE WAVE PER NODE, bf16 gather ----------
__global__ __launch_bounds__(256) void attn_gather(
    const unsigned short* __restrict__ Hb,   // [*,FF] bf16
    const float* __restrict__ alS, const float* __restrict__ alD,
    const int* __restrict__ offs, const int* __restrict__ srcs,
    const float* __restrict__ bias,
    float* __restrict__ out_f32, unsigned short* __restrict__ out_b16, int relu) {
    __shared__ float alpha_sh[4][MAXE][HH];
    __shared__ int   srcs_sh[4][MAXE];
    int w = threadIdx.x >> 6, lane = threadIdx.x & 63;
    int n = blockIdx.x * 4 + w;
    if (n >= NN) return;
    int h = lane >> 3, es = lane & 7;
    int beg = offs[n], end = offs[n + 1], deg = end - beg;

    float ald = alD[n * HH + h];
    float m = -1e30f, den = 0.f, idn;

    if (deg <= MAXE) {
        for (int e = es; e < deg; e += 8) {
            int s = srcs[beg + e];
            if (h == 0) srcs_sh[w][e] = s;
            float sc = alS[s * HH + h] + ald;
            sc = sc > 0.f ? sc : 0.2f * sc;
            alpha_sh[w][e][h] = sc;
            m = fmaxf(m, sc);
        }
        m = fmaxf(m, __shfl_xor(m, 1));
        m = fmaxf(m, __shfl_xor(m, 2));
        m = fmaxf(m, __shfl_xor(m, 4));
        for (int e = es; e < deg; e += 8) {
            float ex = __expf(alpha_sh[w][e][h] - m);
            den += ex;
            alpha_sh[w][e][h] = ex;
        }
        den += __shfl_xor(den, 1);
        den += __shfl_xor(den, 2);
        den += __shfl_xor(den, 4);
        idn = 1.f / (den + 1e-16f);
    } else {
        for (int e = es; e < deg; e += 8) {
            int s = srcs[beg + e];
            float sc = alS[s * HH + h] + ald;
            sc = sc > 0.f ? sc : 0.2f * sc;
            m = fmaxf(m, sc);
        }
        m = fmaxf(m, __shfl_xor(m, 1));
        m = fmaxf(m, __shfl_xor(m, 2));
        m = fmaxf(m, __shfl_xor(m, 4));
        for (int e = es; e < deg; e += 8) {
            int s = srcs[beg + e];
            float sc = alS[s * HH + h] + ald;
            sc = sc > 0.f ? sc : 0.2f * sc;
            den += __expf(sc - m);
        }
        den += __shfl_xor(den, 1);
        den += __shfl_xor(den, 2);
        den += __shfl_xor(den, 4);
        idn = 1.f / (den + 1e-16f);
    }

    int f0 = lane * 8;
    float acc[8] = {};
    if (deg <= MAXE) {
        int e = 0;
        for (; e + 4 <= deg; e += 4) {
            int s0 = srcs_sh[w][e + 0], s1 = srcs_sh[w][e + 1];
            int s2 = srcs_sh[w][e + 2], s3 = srcs_sh[w][e + 3];
            bf16x8 v0 = *(const bf16x8*)&Hb[(size_t)s0 * FF + f0];
            bf16x8 v1 = *(const bf16x8*)&Hb[(size_t)s1 * FF + f0];
            bf16x8 v2 = *(const bf16x8*)&Hb[(size_t)s2 * FF + f0];
            bf16x8 v3 = *(const bf16x8*)&Hb[(size_t)s3 * FF + f0];
            float a0 = alpha_sh[w][e + 0][h], a1 = alpha_sh[w][e + 1][h];
            float a2 = alpha_sh[w][e + 2][h], a3 = alpha_sh[w][e + 3][h];
#pragma unroll
            for (int k = 0; k < 8; ++k) {
                acc[k] += a0 * bf2f((unsigned short)v0[k]);
                acc[k] += a1 * bf2f((unsigned short)v1[k]);
                acc[k] += a2 * bf2f((unsigned short)v2[k]);
                acc[k] += a3 * bf2f((unsigned short)v3[k]);
            }
        }
        for (; e < deg; ++e) {
            int s = srcs_sh[w][e];
            float a = alpha_sh[w][e][h];
            bf16x8 v = *(const bf16x8*)&Hb[(size_t)s * FF + f0];
#pragma unroll
            for (int k = 0; k < 8; ++k)
                acc[k] += a * bf2f((unsigned short)v[k]);
        }
#pragma unroll
        for (int k = 0; k < 8; ++k) acc[k] *= idn;
    } else {
        for (int e = 0; e < deg; ++e) {
            int s = srcs[beg + e];
            float sc = alS[s * HH + h] + ald;
            sc = sc > 0.f ? sc : 0.2f * sc;
            float a = __expf(sc - m) * idn;
            bf16x8 v = *(const bf16x8*)&Hb[(size_t)s * FF + f0];
#pragma unroll
            for (int k = 0; k < 8; ++k)
                acc[k] += a * bf2f((unsigned short)v[k]);
        }
    }
    float4 b0 = *(const float4*)&bias[f0];
    float4 b1 = *(const float4*)&bias[f0 + 4];
    float bv[8] = {b0.x, b0.y, b0.z, b0.w, b1.x, b1.y, b1.z, b1.w};
    float vv[8];
#pragma unroll
    for (int k = 0; k < 8; ++k) {
        float t = acc[k] + bv[k];
        vv[k] = relu ? fmaxf(t, 0.f) : t;
    }
    if (out_f32) {
        float4 o0 = {vv[0], vv[1], vv[2], vv[3]};
        float4 o1 = {vv[4], vv[5], vv[6], vv[7]};
        *(float4*)&out_f32[(size_t)n * FF + f0] = o0;
        *(float4*)&out_f32[(size_t)n * FF + f0 + 4] = o1;
    }
    if (out_b16) {
        s16x8 ov;
#pragma unroll
        for (int k = 0; k < 8; ++k) ov[k] = (short)f2bf(vv[k]);
        *(s16x8*)&out_b16[(size_t)n * FF + f0] = ov;
    }
}

// ---------------- bf16 MFMA GEMM + fused logits, bf16 output (2-phase dbuf) ---
// Used for layer 1 (K=64, xb/W1T) AND layer 2 (K=512). dbuf + L2-affinity
// swizzle; NT=1 degenerates cleanly (no prefetch).
__global__ __launch_bounds__(256) void gemm_mfma(
    const unsigned short* __restrict__ A,   // [MP][K] bf16
    const unsigned short* __restrict__ BT,  // [N][K]  bf16
    const float* __restrict__ a_s, const float* __restrict__ a_d,  // [N]
    unsigned short* __restrict__ Cb,        // [MP][N] bf16
    float* __restrict__ alS, float* __restrict__ alD,              // [MP][HH]
    int N, int K) {
    __shared__ unsigned short As[2][128 * 64];
    __shared__ unsigned short Bs[2][128 * 64];
    int t = threadIdx.x;
    int wave = t >> 6, lane = t & 63;
    int wr = wave >> 1, wc = wave & 1;

    // bijective bid -> (mt, nt): same-m blocks 8 apart in dispatch order.
    int bid = blockIdx.x;
    int mt, nt;
    if (bid < (MT2 / 8) * 32) {
        int g = bid >> 5, r = bid & 31;
        mt = g * 8 + (r & 7);
        nt = r >> 3;
    } else {
        int t2 = bid - (MT2 / 8) * 32;
        mt = (MT2 / 8) * 8 + (t2 >> 2);
        nt = t2 & 3;
    }
    int m0 = mt * 128, n0 = nt * 128;

    f32x4 acc[4][4] = {};
    int kg = lane >> 4;
    int lr = lane & 15;

    auto STAGE = [&](int buf, int k0) {
#pragma unroll
        for (int q = 0; q < 4; ++q) {
            int c   = q * 256 + t;
            int row = c >> 3, kc = c & 7;
            int kcs = kc ^ (row & 7);
            const unsigned short* ga = A + (size_t)(m0 + row) * K + k0 + kcs * 8;
            const unsigned short* gb = BT + (size_t)(n0 + row) * K + k0 + kcs * 8;
            unsigned short* la = &As[buf][(size_t)(q * 256 + wave * 64) * 8];
            unsigned short* lb = &Bs[buf][(size_t)(q * 256 + wave * 64) * 8];
            __builtin_amdgcn_global_load_lds(
                (const __attribute__((address_space(1))) void*)ga,
                (__attribute__((address_space(3))) void*)la, 16, 0, 0);
            __builtin_amdgcn_global_load_lds(
                (const __attribute__((address_space(1))) void*)gb,
                (__attribute__((address_space(3))) void*)lb, 16, 0, 0);
        }
    };

    const int NT = K / 64;
    STAGE(0, 0);
    __syncthreads();
    int cur = 0;
    for (int kt = 0; kt < NT; ++kt) {
        if (kt + 1 < NT) STAGE(cur ^ 1, (kt + 1) * 64);
        const unsigned short* Ac = As[cur];
        const unsigned short* Bc = Bs[cur];
#pragma unroll
        for (int ks = 0; ks < 2; ++ks) {
            bf16x8 af[4], bf[4];
#pragma unroll
            for (int i = 0; i < 4; ++i) {
                int rowa = wr * 64 + i * 16 + lr;
                af[i] = *(const bf16x8*)&Ac[rowa * 64 + (((ks << 2) | kg) ^ (rowa & 7)) * 8];
                int rowb = wc * 64 + i * 16 + lr;
                bf[i] = *(const bf16x8*)&Bc[rowb * 64 + (((ks << 2) | kg) ^ (rowb & 7)) * 8];
            }
#pragma unroll
            for (int i = 0; i < 4; ++i)
#pragma unroll
                for (int j = 0; j < 4; ++j)
                    acc[i][j] = __builtin_amdgcn_mfma_f32_16x16x32_bf16(
                        af[i], bf[j], acc[i][j], 0, 0, 0);
        }
        __syncthreads();   // drains prefetch vmcnt + compute lgkm; buffers swap
        cur ^= 1;
    }

    // ---- fused attention logits: head = n0/64 + wc ----
    int head = (n0 >> 6) + wc;
    float asv[4], adv[4];
#pragma unroll
    for (int j = 0; j < 4; ++j) {
        int cc = n0 + wc * 64 + j * 16 + lr;
        asv[j] = a_s[cc];
        adv[j] = a_d[cc];
    }
#pragma unroll
    for (int i = 0; i < 4; ++i) {
#pragma unroll
        for (int reg = 0; reg < 4; ++reg) {
            float ps = 0.f, pd = 0.f;
#pragma unroll
            for (int j = 0; j < 4; ++j) {
                ps += acc[i][j][reg] * asv[j];
                pd += acc[i][j][reg] * adv[j];
            }
#pragma unroll
            for (int d = 1; d < 16; d <<= 1) {
                ps += __shfl_xor(ps, d);
                pd += __shfl_xor(pd, d);
            }
            if (lr == 0) {
                int r = m0 + wr * 64 + i * 16 + kg * 4 + reg;
                alS[(size_t)r * HH + head] = ps;
                alD[(size_t)r * HH + head] = pd;
            }
        }
    }

#pragma unroll
    for (int i = 0; i < 4; ++i) {
        int rb = m0 + wr * 64 + i * 16 + kg * 4;
#pragma unroll
        for (int j = 0; j < 4; ++j) {
            int cc = n0 + wc * 64 + j * 16 + lr;
#pragma unroll
            for (int reg = 0; reg < 4; ++reg)
                Cb[(size_t)(rb + reg) * N + cc] = f2bf(acc[i][j][reg]);
        }
    }
}

// ---------------- layer-3 MFMA GEMM + fused al40 logits ----------------------
// h3[MP,40] = A[MP,512] @ W3T[48,512]^T ; epilogue stages the C-tile in LDS and
// computes alS/alD (per row, head) from it -> kills the al40 pass.
__global__ __launch_bounds__(256) void gemm3_mfma(
    const unsigned short* __restrict__ A,    // [MP][512] bf16
    const unsigned short* __restrict__ BT,   // [48][512] bf16
    const float* __restrict__ as3, const float* __restrict__ ad3,  // [40]
    float* __restrict__ C,                   // [NN][40] f32
    float* __restrict__ alS, float* __restrict__ alD) {            // [*][HH]
    __shared__ unsigned short As[128 * 64];
    __shared__ unsigned short Bs[48 * 64];
    __shared__ float cls[128][F3];
    int t = threadIdx.x;
    int wave = t >> 6, lane = t & 63;
    int m0 = blockIdx.x * 128;
    int kg = lane >> 4, lr = lane & 15;

    f32x4 acc[2][3] = {};

    for (int k0 = 0; k0 < 512; k0 += 64) {
#pragma unroll
        for (int q = 0; q < 4; ++q) {
            int c   = q * 256 + t;
            int row = c >> 3, kc = c & 7;
            int kcs = kc ^ (row & 7);
            const unsigned short* ga = A + (size_t)(m0 + row) * 512 + k0 + kcs * 8;
            unsigned short* la = &As[(size_t)(q * 256 + wave * 64) * 8];
            __builtin_amdgcn_global_load_lds(
                (const __attribute__((address_space(1))) void*)ga,
                (__attribute__((address_space(3))) void*)la, 16, 0, 0);
        }
        {
            int c   = t;
            int row = c >> 3, kc = c & 7;
            int kcs = kc ^ (row & 7);
            const unsigned short* gb = BT + (size_t)row * 512 + k0 + kcs * 8;
            unsigned short* lb = &Bs[(size_t)(wave * 64) * 8];
            __builtin_amdgcn_global_load_lds(
                (const __attribute__((address_space(1))) void*)gb,
                (__attribute__((address_space(3))) void*)lb, 16, 0, 0);
        }
        if (t < 128) {
            int c   = 256 + t;
            int row = c >> 3, kc = c & 7;
            int kcs = kc ^ (row & 7);
            const unsigned short* gb = BT + (size_t)row * 512 + k0 + kcs * 8;
            unsigned short* lb = &Bs[(size_t)(256 + wave * 64) * 8];
            __builtin_amdgcn_global_load_lds(
                (const __attribute__((address_space(1))) void*)gb,
                (__attribute__((address_space(3))) void*)lb, 16, 0, 0);
        }
        __syncthreads();
#pragma unroll
        for (int ks = 0; ks < 2; ++ks) {
            bf16x8 af[2], bf[3];
#pragma unroll
            for (int i = 0; i < 2; ++i) {
                int rowa = wave * 32 + i * 16 + lr;
                af[i] = *(const bf16x8*)&As[rowa * 64 + (((ks << 2) | kg) ^ (rowa & 7)) * 8];
            }
#pragma unroll
            for (int j = 0; j < 3; ++j) {
                int rowb = j * 16 + lr;
                bf[j] = *(const bf16x8*)&Bs[rowb * 64 + (((ks << 2) | kg) ^ (rowb & 7)) * 8];
            }
#pragma unroll
            for (int i = 0; i < 2; ++i)
#pragma unroll
                for (int j = 0; j < 3; ++j)
                    acc[i][j] = __builtin_amdgcn_mfma_f32_16x16x32_bf16(
                        af[i], bf[j], acc[i][j], 0, 0, 0);
        }
        __syncthreads();
    }

    // epilogue: global store + LDS stash
#pragma unroll
    for (int i = 0; i < 2; ++i) {
        int rloc = wave * 32 + i * 16 + kg * 4;
#pragma unroll
        for (int j = 0; j < 3; ++j) {
            int cc = j * 16 + lr;
            if (cc >= F3) continue;
#pragma unroll
            for (int reg = 0; reg < 4; ++reg) {
                int rl = rloc + reg;
                cls[rl][cc] = acc[i][j][reg];
                int r = m0 + rl;
                if (r < NN) C[(size_t)r * F3 + cc] = acc[i][j][reg];
            }
        }
    }
    __syncthreads();

    // fused al40: 128 rows x 8 heads = 1024 (row,head) pairs
    for (int p2 = t; p2 < 128 * HH; p2 += 256) {
        int rl = p2 >> 3, hh = p2 & 7;
        int r = m0 + rl;
        if (r >= NN) continue;
        float s = 0.f, d = 0.f;
#pragma unroll
        for (int c = 0; c < C3; ++c) {
            float v = cls[rl][hh * C3 + c];
            s += v * as3[hh * C3 + c];
            d += v * ad3[hh * C3 + c];
        }
        alS[(size_t)r * HH + hh] = s;
        alD[(size_t)r * HH + hh] = d;
    }
}

// ---------------- layer-3 attention, wave-parallel (4 nodes/block) ------------
__global__ __launch_bounds__(256) void attn3_kernel(
    const float* __restrict__ h3, const float* __restrict__ al_s,
    const float* __restrict__ al_d, const int* __restrict__ offs,
    const int* __restrict__ srcs, const float* __restrict__ b3,
    float* __restrict__ out) {
    __shared__ float alpha_sh[4][MAXE][HH];
    __shared__ int   srcs_sh[4][MAXE];
    __shared__ float idn_sh[4][HH], m_sh[4][HH], ald_sh2[4][HH];
    __shared__ float accs[4][F3];
    __shared__ float vv[4][C3];
    int w = threadIdx.x >> 6, lane = threadIdx.x & 63;
    int n = blockIdx.x * 4 + w;
    int h = lane >> 3, es = lane & 7;
    int beg = offs[n], end = offs[n + 1], deg = end - beg;

    float ald = al_d[n * HH + h];
    float m = -1e30f, den = 0.f, idn;
    if (deg <= MAXE) {
        for (int e = es; e < deg; e += 8) {
            int s = srcs[beg + e];
            if (h == 0) srcs_sh[w][e] = s;
            float sc = al_s[s * HH + h] + ald;
            sc = sc > 0.f ? sc : 0.2f * sc;
            alpha_sh[w][e][h] = sc;
            m = fmaxf(m, sc);
        }
        m = fmaxf(m, __shfl_xor(m, 1));
        m = fmaxf(m, __shfl_xor(m, 2));
        m = fmaxf(m, __shfl_xor(m, 4));
        for (int e = es; e < deg; e += 8) {
            float ex = __expf(alpha_sh[w][e][h] - m);
            den += ex;
            alpha_sh[w][e][h] = ex;
        }
        den += __shfl_xor(den, 1);
        den += __shfl_xor(den, 2);
        den += __shfl_xor(den, 4);
        idn = 1.f / (den + 1e-16f);
        if (es == 0) idn_sh[w][h] = idn;
    } else {
        for (int e = es; e < deg; e += 8) {
            int s = srcs[beg + e];
            float sc = al_s[s * HH + h] + ald;
            sc = sc > 0.f ? sc : 0.2f * sc;
            m = fmaxf(m, sc);
        }
        m = fmaxf(m, __shfl_xor(m, 1));
        m = fmaxf(m, __shfl_xor(m, 2));
        m = fmaxf(m, __shfl_xor(m, 4));
        for (int e = es; e < deg; e += 8) {
            int s = srcs[beg + e];
            float sc = al_s[s * HH + h] + ald;
            sc = sc > 0.f ? sc : 0.2f * sc;
            den += __expf(sc - m);
        }
        den += __shfl_xor(den, 1);
        den += __shfl_xor(den, 2);
        den += __shfl_xor(den, 4);
        idn = 1.f / (den + 1e-16f);
        if (es == 0) { idn_sh[w][h] = idn; m_sh[w][h] = m; ald_sh2[w][h] = ald; }
    }
    __syncthreads();

    if (lane < F3) {
        int hh = lane / C3;
        float acc = 0.f;
        if (deg <= MAXE) {
            int e = 0;
            for (; e + 4 <= deg; e += 4) {
                int s0 = srcs_sh[w][e + 0], s1 = srcs_sh[w][e + 1];
                int s2 = srcs_sh[w][e + 2], s3 = srcs_sh[w][e + 3];
                float v0 = h3[(size_t)s0 * F3 + lane];
                float v1 = h3[(size_t)s1 * F3 + lane];
                float v2 = h3[(size_t)s2 * F3 + lane];
                float v3 = h3[(size_t)s3 * F3 + lane];
                acc += alpha_sh[w][e + 0][hh] * v0 + alpha_sh[w][e + 1][hh] * v1
                     + alpha_sh[w][e + 2][hh] * v2 + alpha_sh[w][e + 3][hh] * v3;
            }
            for (; e < deg; ++e) {
                int s = srcs_sh[w][e];
                acc += alpha_sh[w][e][hh] * h3[(size_t)s * F3 + lane];
            }
        } else {
            float mm = m_sh[w][hh], aald = ald_sh2[w][hh];
            for (int e = 0; e < deg; ++e) {
                int s = srcs[beg + e];
                float sc = al_s[s * HH + hh] + aald;
                sc = sc > 0.f ? sc : 0.2f * sc;
                acc += __expf(sc - mm) * h3[(size_t)s * F3 + lane];
            }
        }
        accs[w][lane] = acc * idn_sh[w][hh];
    }
    __syncthreads();
    if (lane < C3) {
        float s = 0.f;
#pragma unroll
        for (int hh = 0; hh < HH; ++hh) s += accs[w][hh * C3 + lane];
        vv[w][lane] = s * 0.125f + b3[lane];
    }
    __syncthreads();
    if (lane < C3) {
        float mx = vv[w][0];
#pragma unroll
        for (int c = 1; c < C3; ++c) mx = fmaxf(mx, vv[w][c]);
        float se = 0.f;
#pragma unroll
        for (int c = 0; c < C3; ++c) se += __expf(vv[w][c] - mx);
        out[(size_t)n * C3 + lane] = vv[w][lane] - mx - logf(se);
    }
}

// ---------------- host launcher ----------------
extern "C" void kernel_launch(void* const* d_in, const int* in_sizes, int n_in,
                              void* d_out, int out_size, void* d_ws, size_t ws_size,
                              hipStream_t stream) {
    const float* x   = (const float*)d_in[0];
    const int*   ei  = (const int*)d_in[1];
    const float* W1  = (const float*)d_in[2];
    const float* as1 = (const float*)d_in[3];
    const float* ad1 = (const float*)d_in[4];
    const float* b1  = (const float*)d_in[5];
    const float* W2  = (const float*)d_in[6];
    const float* as2 = (const float*)d_in[7];
    const float* ad2 = (const float*)d_in[8];
    const float* b2  = (const float*)d_in[9];
    const float* W3  = (const float*)d_in[10];
    const float* as3 = (const float*)d_in[11];
    const float* ad3 = (const float*)d_in[12];
    const float* b3  = (const float*)d_in[13];
    float* out = (float*)d_out;

    // ---- workspace layout (lifetime-aliased, ~125 MB) ----
    auto au = [](size_t v) { return (v + 255) & ~(size_t)255; };
    char* p = (char*)d_ws;
    size_t szHb = au((size_t)MP * FF * 2);           // 51.25 MB
    char* r1 = p;
    unsigned short* Hb1 = (unsigned short*)r1;
    unsigned short* Hb2 = (unsigned short*)r1;
    p += szHb;
    char* r2 = p;
    unsigned short* A2   = (unsigned short*)r2;
    unsigned short* Bb16 = (unsigned short*)r2;      // alias: attn2 out
    unsigned short* W2T  = (unsigned short*)(r2 + szHb);
    p = r2 + szHb + au((size_t)FF * FF * 2);
    unsigned short* W3T = (unsigned short*)p;  p += au((size_t)48 * 512 * 2);
    unsigned short* W1T = (unsigned short*)p;  p += au((size_t)512 * 64 * 2);
    unsigned short* xb  = (unsigned short*)p;  p += au((size_t)MP * 64 * 2);
    float* alS  = (float*)p;  p += au((size_t)MP * HH * 4);
    float* alD  = (float*)p;  p += au((size_t)MP * HH * 4);
    float* h3   = (float*)p;  p += au((size_t)NN * F3 * 4);
    int* offs   = (int*)p;    p += au((size_t)(NN + 1) * 4);
    int* cnt    = (int*)p;    p += au((size_t)NN * 4);
    int* srcs   = (int*)p;    p += au((size_t)ETOT * 4);
    int* bsum   = (int*)p;    p += au(64 * 4);

    // ---- CSR build (dst-sorted) + prep ----
    hipMemsetAsync(cnt, 0, (size_t)NN * 4, stream);
    count_kernel<<<(ETOT + 255) / 256, 256, 0, stream>>>(ei, cnt);
    scan_blocks<<<NBLK, 1024, 0, stream>>>(cnt, offs, bsum);  // also re-zeros cnt
    scan_add<<<NBLK, 1024, 0, stream>>>(offs, bsum);
    scatter_kernel<<<(ETOT + 255) / 256, 256, 0, stream>>>(ei, offs, cnt, srcs);
    {
        long long prep_elems = (long long)FF * FF + 48 * 512 + (long long)(MP - NN) * FF
                             + 512 * 64 + (long long)MP * 64;
        prep_all<<<(int)((prep_elems + 255) / 256), 256, 0, stream>>>(
            W2, W3, W1, x, W2T, W3T, W1T, xb, A2);
    }

    // ---- layer 1: MFMA GEMM (K padded to 64) + fused logits ----
    gemm_mfma<<<GT2, 256, 0, stream>>>(
        xb, W1T, as1, ad1, Hb1, alS, alD, FF, 64);
    attn_gather<<<(NN + 3) / 4, 256, 0, stream>>>(Hb1, alS, alD, offs, srcs, b1,
                                                  nullptr, A2, 1);

    // ---- layer 2: bf16 MFMA GEMM (+ fused logits), dbuf + L2-affinity swizzle
    gemm_mfma<<<GT2, 256, 0, stream>>>(
        A2, W2T, as2, ad2, Hb2, alS, alD, FF, FF);
    attn_gather<<<(NN + 3) / 4, 256, 0, stream>>>(Hb2, alS, alD, offs, srcs, b2,
                                                  nullptr, Bb16, 1);

    // ---- layer 3: MFMA GEMM + fused al40 logits ----
    gemm3_mfma<<<MP / 128, 256, 0, stream>>>(Bb16, W3T, as3, ad3, h3, alS, alD);
    attn3_kernel<<<NN / 4, 256, 0, stream>>>(h3, alS, alD, offs, srcs, b3, out);
}